// Round 1
// baseline (308.949 us; speedup 1.0000x reference)
//
#include <hip/hip_runtime.h>

#define DM 1024
#define DH 64
#define NBATCH 4
#define NCTX 4096
#define MTOT (NBATCH*NCTX)

typedef __bf16 bf16x8 __attribute__((ext_vector_type(8)));
typedef float f32x4 __attribute__((ext_vector_type(4)));

#define MFMA16(a,b,c) __builtin_amdgcn_mfma_f32_16x16x32_bf16(a,b,c,0,0,0)

#define GLDS16(g, l) __builtin_amdgcn_global_load_lds( \
    (const __attribute__((address_space(1))) void*)(g), \
    (__attribute__((address_space(3))) void*)(l), 16, 0, 0)

__device__ inline ushort f2bf(float f) {
  unsigned u = __builtin_bit_cast(unsigned, f);
  u += 0x7fffu + ((u >> 16) & 1u);
  return (ushort)(u >> 16);
}

// ---------------- kernel 0: weight fp32 -> bf16 ----------------
// wqkv: [192][1024] rows 0..63=Wq, 64..127=Wk, 128..191=Wov ; wo: [1024][64]
__global__ __launch_bounds__(256) void wconv_kernel(
    const float* __restrict__ Wq, const float* __restrict__ Wk,
    const float* __restrict__ Wov, const float* __restrict__ Wo,
    ushort* __restrict__ wqkv, ushort* __restrict__ wo)
{
  int idx = (blockIdx.x * 256 + threadIdx.x) * 4;
  if (idx < 196608) {
    const float* src = (idx < 65536) ? (Wq + idx)
                     : (idx < 131072 ? (Wk + (idx - 65536)) : (Wov + (idx - 131072)));
    float4 v = *(const float4*)src;
    ushort4 o = { f2bf(v.x), f2bf(v.y), f2bf(v.z), f2bf(v.w) };
    *(ushort4*)(wqkv + idx) = o;
  } else {
    int j = idx - 196608;
    float4 v = *(const float4*)(Wo + j);
    ushort4 o = { f2bf(v.x), f2bf(v.y), f2bf(v.z), f2bf(v.w) };
    *(ushort4*)(wo + j) = o;
  }
}

// ---------------- kernel 1: QKV projection ----------------
// C[m, 0:192] = x[m, :] @ wqkv^T ; Q pre-scaled by log2e/32, V written transposed.
__global__ __launch_bounds__(256) void qkv_kernel(
    const float* __restrict__ x, const ushort* __restrict__ wqkv,
    const float* __restrict__ bq, const float* __restrict__ bk,
    const float* __restrict__ bov,
    ushort* __restrict__ Qo, ushort* __restrict__ Ko, ushort* __restrict__ Vt)
{
  __shared__ __attribute__((aligned(16))) ushort xs[32 * 64];  // swizzled bf16 tile
  const int tid  = threadIdx.x;
  const int lane = tid & 63;
  const int wave = tid >> 6;
  const int mt   = wave & 1;   // m-tile 0/1 (16 rows each)
  const int nh   = wave >> 1;  // n-half: nt = nh*6 .. nh*6+5
  const int l15  = lane & 15;
  const int l4   = lane >> 4;
  const int row0 = blockIdx.x * 32;

  f32x4 acc[6] = {};

  for (int kc = 0; kc < DM; kc += 64) {
    // stage x[row0:row0+32, kc:kc+64] -> bf16, XOR-swizzled rows (128B rows)
    #pragma unroll
    for (int j = 0; j < 2; ++j) {
      int f4  = tid + j * 256;     // 0..511 float4s
      int row = f4 >> 4;
      int c4  = f4 & 15;
      float4 v = *(const float4*)(x + (size_t)(row0 + row) * DM + kc + c4 * 4);
      ushort4 o = { f2bf(v.x), f2bf(v.y), f2bf(v.z), f2bf(v.w) };
      int byteoff = row * 128 + ((c4 * 8) ^ ((row & 7) << 4));
      *(ushort4*)((char*)xs + byteoff) = o;
    }
    __syncthreads();
    #pragma unroll
    for (int c = 0; c < 2; ++c) {
      int arow  = mt * 16 + l15;
      int abyte = arow * 128 + ((((c * 4 + l4)) ^ (arow & 7)) << 4);
      bf16x8 a = *(const bf16x8*)((const char*)xs + abyte);
      #pragma unroll
      for (int i = 0; i < 6; ++i) {
        int nt = nh * 6 + i;
        int brow = nt * 16 + l15;
        bf16x8 b = *(const bf16x8*)(wqkv + (size_t)brow * DM + kc + c * 32 + l4 * 8);
        acc[i] = MFMA16(a, b, acc[i]);
      }
    }
    __syncthreads();
  }

  const float qscale = 1.4426950408889634f / 32.0f;  // log2(e)/sqrt(d_model)
  #pragma unroll
  for (int i = 0; i < 6; ++i) {
    int nt = nh * 6 + i;
    int n  = nt * 16 + l15;
    #pragma unroll
    for (int r = 0; r < 4; ++r) {
      int grow = row0 + mt * 16 + l4 * 4 + r;
      float v = acc[i][r];
      if (n < 64) {
        Qo[(size_t)grow * 64 + n] = f2bf((v + bq[n]) * qscale);
      } else if (n < 128) {
        int nn = n - 64;
        Ko[(size_t)grow * 64 + nn] = f2bf(v + bk[nn]);
      } else {
        int nn = n - 128;
        int b = grow >> 12, pos = grow & 4095;
        Vt[((size_t)b * 64 + nn) * NCTX + pos] = f2bf(v + bov[nn]);
      }
    }
  }
}

// ---------------- kernel 2: causal flash attention ----------------
// QBLK=32 (2 waves x 16 rows), KVBLK=64. Longest-first block order for balance.
__global__ __launch_bounds__(128) void attn_kernel(
    const ushort* __restrict__ Q, const ushort* __restrict__ K,
    const ushort* __restrict__ Vt, ushort* __restrict__ O)
{
  __shared__ __attribute__((aligned(16))) ushort Ks[64 * 64];
  __shared__ __attribute__((aligned(16))) ushort Vs[64 * 64];   // V^T tile [d][kv]
  __shared__ __attribute__((aligned(16))) ushort Ps[2][16 * 64];

  const int tid  = threadIdx.x;
  const int lane = tid & 63;
  const int wave = tid >> 6;
  const int l15  = lane & 15;
  const int l4   = lane >> 4;

  // block -> (batch, q-tile): first 256 blocks take long tiles (t=64..127)
  int i = blockIdx.x;
  int half = i >> 8, j = i & 255;
  int bb = j & 3, tt = j >> 2;
  int t = half ? (63 - tt) : (64 + tt);

  const ushort* Qb  = Q  + (size_t)bb * NCTX * 64;
  const ushort* Kb  = K  + (size_t)bb * NCTX * 64;
  const ushort* Vtb = Vt + (size_t)bb * 64 * NCTX;
  ushort* Ob = O + (size_t)bb * NCTX * 64;

  const int q0  = t * 32;
  const int qs0 = q0 + wave * 16;  // this wave's 16-row strip

  bf16x8 qf[2];
  #pragma unroll
  for (int c = 0; c < 2; ++c)
    qf[c] = *(const bf16x8*)(Qb + (size_t)(qs0 + l15) * 64 + c * 32 + l4 * 8);

  float m_run[4], l_run[4];
  f32x4 accO[4] = {};
  #pragma unroll
  for (int r = 0; r < 4; ++r) { m_run[r] = -1e30f; l_run[r] = 0.f; }

  const int nkv = (32 * t + 95) >> 6;
  for (int it = 0; it < nkv; ++it) {
    const int kv0 = it * 64;
    // stage K tile [64 kv][64 d] and V^T tile [64 d][64 kv], XOR-swizzled via
    // pre-swizzled GLOBAL source + linear LDS dest (global_load_lds rule).
    #pragma unroll
    for (int s = 0; s < 4; ++s) {
      int base = s * 2048 + wave * 1024;       // wave-uniform LDS byte base
      int dbyte = base + lane * 16;
      int row = dbyte >> 7;
      int ch  = (dbyte >> 4) & 7;
      int sch = ch ^ (row & 7);
      GLDS16(Kb  + (size_t)(kv0 + row) * 64 + sch * 8, (char*)Ks + base);
      GLDS16(Vtb + (size_t)row * NCTX + kv0 + sch * 8, (char*)Vs + base);
    }
    __syncthreads();

    // S = Q K^T  (16 q rows x 64 kv)
    f32x4 s4[4] = {};
    #pragma unroll
    for (int c = 0; c < 2; ++c) {
      #pragma unroll
      for (int nt = 0; nt < 4; ++nt) {
        int brow  = nt * 16 + l15;
        int bbyte = brow * 128 + (((c * 4 + l4) ^ (brow & 7)) << 4);
        bf16x8 kb = *(const bf16x8*)((const char*)Ks + bbyte);
        s4[nt] = MFMA16(qf[c], kb, s4[nt]);
      }
    }
    // causal mask (only tiles crossing the diagonal of this strip)
    if (kv0 + 63 > qs0) {
      #pragma unroll
      for (int nt = 0; nt < 4; ++nt) {
        int kvg = kv0 + nt * 16 + l15;
        #pragma unroll
        for (int r = 0; r < 4; ++r) {
          int qg = qs0 + l4 * 4 + r;
          if (kvg > qg) s4[nt][r] = -1e30f;
        }
      }
    }
    // online softmax (base-2 domain; Q pre-scaled by log2e/32)
    float alpha[4];
    #pragma unroll
    for (int r = 0; r < 4; ++r) {
      float mx = fmaxf(fmaxf(s4[0][r], s4[1][r]), fmaxf(s4[2][r], s4[3][r]));
      mx = fmaxf(mx, __shfl_xor(mx, 1));
      mx = fmaxf(mx, __shfl_xor(mx, 2));
      mx = fmaxf(mx, __shfl_xor(mx, 4));
      mx = fmaxf(mx, __shfl_xor(mx, 8));
      float mn = fmaxf(m_run[r], mx);
      alpha[r] = exp2f(m_run[r] - mn);
      m_run[r] = mn;
      float sm = 0.f;
      #pragma unroll
      for (int nt = 0; nt < 4; ++nt) {
        float p = exp2f(s4[nt][r] - mn);
        s4[nt][r] = p;
        sm += p;
      }
      sm += __shfl_xor(sm, 1); sm += __shfl_xor(sm, 2);
      sm += __shfl_xor(sm, 4); sm += __shfl_xor(sm, 8);
      l_run[r] = l_run[r] * alpha[r] + sm;
      #pragma unroll
      for (int dt = 0; dt < 4; ++dt) accO[dt][r] *= alpha[r];
    }
    // P -> per-wave swizzled LDS (to reach A-fragment layout)
    ushort* Pw = (ushort*)Ps[wave];
    #pragma unroll
    for (int nt = 0; nt < 4; ++nt) {
      int kv = nt * 16 + l15;
      #pragma unroll
      for (int r = 0; r < 4; ++r) {
        int prow = l4 * 4 + r;
        int pbyte = prow * 128 + ((kv * 2) ^ ((prow & 7) << 4));
        *(ushort*)((char*)Pw + pbyte) = f2bf(s4[nt][r]);
      }
    }
    // O += P @ V  (V^T rows as B operand)
    #pragma unroll
    for (int c = 0; c < 2; ++c) {
      int abyte = l15 * 128 + (((c * 4 + l4) ^ (l15 & 7)) << 4);
      bf16x8 pa = *(const bf16x8*)((const char*)Pw + abyte);
      #pragma unroll
      for (int dt = 0; dt < 4; ++dt) {
        int vrow  = dt * 16 + l15;
        int vbyte = vrow * 128 + (((c * 4 + l4) ^ (vrow & 7)) << 4);
        bf16x8 vb = *(const bf16x8*)((const char*)Vs + vbyte);
        accO[dt] = MFMA16(pa, vb, accO[dt]);
      }
    }
    __syncthreads();
  }

  #pragma unroll
  for (int r = 0; r < 4; ++r) {
    float inv = 1.0f / l_run[r];
    int qrow = qs0 + l4 * 4 + r;
    #pragma unroll
    for (int dt = 0; dt < 4; ++dt) {
      Ob[(size_t)qrow * 64 + dt * 16 + l15] = f2bf(accO[dt][r] * inv);
    }
  }
}

// ---------------- kernel 3: output projection ----------------
// out[m, n] = O[m, :] @ Wo[n, :] + bo[n]
__global__ __launch_bounds__(256) void proj_kernel(
    const ushort* __restrict__ O, const ushort* __restrict__ wo,
    const float* __restrict__ bo, float* __restrict__ out)
{
  const int tid  = threadIdx.x;
  const int lane = tid & 63;
  const int wave = tid >> 6;
  const int l15  = lane & 15;
  const int l4   = lane >> 4;
  const int mb = (blockIdx.x >> 2) * 64;
  const int nb = (blockIdx.x & 3) * 256;

  bf16x8 a[2];
  #pragma unroll
  for (int c = 0; c < 2; ++c)
    a[c] = *(const bf16x8*)(O + (size_t)(mb + wave * 16 + l15) * 64 + c * 32 + l4 * 8);

  f32x4 acc[16] = {};
  #pragma unroll
  for (int nt = 0; nt < 16; ++nt) {
    int n = nb + nt * 16 + l15;
    #pragma unroll
    for (int c = 0; c < 2; ++c) {
      bf16x8 b = *(const bf16x8*)(wo + (size_t)n * 64 + c * 32 + l4 * 8);
      acc[nt] = MFMA16(a[c], b, acc[nt]);
    }
  }
  #pragma unroll
  for (int nt = 0; nt < 16; ++nt) {
    int n = nb + nt * 16 + l15;
    float bv = bo[n];
    #pragma unroll
    for (int r = 0; r < 4; ++r) {
      int m = mb + wave * 16 + l4 * 4 + r;
      out[(size_t)m * 1024 + n] = acc[nt][r] + bv;
    }
  }
}

extern "C" void kernel_launch(void* const* d_in, const int* in_sizes, int n_in,
                              void* d_out, int out_size, void* d_ws, size_t ws_size,
                              hipStream_t stream) {
  const float* x   = (const float*)d_in[0];
  const float* Wq  = (const float*)d_in[1];
  const float* bq  = (const float*)d_in[2];
  const float* Wk  = (const float*)d_in[3];
  const float* bk  = (const float*)d_in[4];
  const float* Wov = (const float*)d_in[5];
  const float* bov = (const float*)d_in[6];
  const float* Wo  = (const float*)d_in[7];
  const float* bo  = (const float*)d_in[8];
  float* out = (float*)d_out;

  char* ws = (char*)d_ws;
  ushort* wqkv = (ushort*)(ws);                              // 192*1024*2 = 393216 B
  ushort* wo   = (ushort*)(ws + 393216);                     // 1024*64*2  = 131072 B
  ushort* Qw   = (ushort*)(ws + 524288);                     // 16384*64*2 = 2 MiB
  ushort* Kw   = (ushort*)(ws + 524288 + 2097152);
  ushort* Vtw  = (ushort*)(ws + 524288 + 2 * 2097152);       // [4][64][4096]
  ushort* Ow   = (ushort*)(ws + 524288 + 3 * 2097152);       // total ~8.5 MiB

  wconv_kernel<<<256, 256, 0, stream>>>(Wq, Wk, Wov, Wo, wqkv, wo);
  qkv_kernel<<<512, 256, 0, stream>>>(x, wqkv, bq, bk, bov, Qw, Kw, Vtw);
  attn_kernel<<<512, 128, 0, stream>>>(Qw, Kw, Vtw, Ow);
  proj_kernel<<<1024, 256, 0, stream>>>(Ow, wo, bo, out);
}

// Round 2
// 270.363 us; speedup vs baseline: 1.1427x; 1.1427x over previous
//
#include <hip/hip_runtime.h>

#define DM 1024
#define DH 64
#define NBATCH 4
#define NCTX 4096
#define MTOT (NBATCH*NCTX)

typedef __bf16 bf16x8 __attribute__((ext_vector_type(8)));
typedef float f32x4 __attribute__((ext_vector_type(4)));

#define MFMA16(a,b,c) __builtin_amdgcn_mfma_f32_16x16x32_bf16(a,b,c,0,0,0)

#define GLDS16(g, l) __builtin_amdgcn_global_load_lds( \
    (const __attribute__((address_space(1))) void*)(g), \
    (__attribute__((address_space(3))) void*)(l), 16, 0, 0)

__device__ inline ushort f2bf(float f) {
  unsigned u = __builtin_bit_cast(unsigned, f);
  u += 0x7fffu + ((u >> 16) & 1u);
  return (ushort)(u >> 16);
}

// ---------------- kernel 0: weight fp32 -> bf16 ----------------
__global__ __launch_bounds__(256) void wconv_kernel(
    const float* __restrict__ Wq, const float* __restrict__ Wk,
    const float* __restrict__ Wov, const float* __restrict__ Wo,
    ushort* __restrict__ wqkv, ushort* __restrict__ wo)
{
  int idx = (blockIdx.x * 256 + threadIdx.x) * 4;
  if (idx < 196608) {
    const float* src = (idx < 65536) ? (Wq + idx)
                     : (idx < 131072 ? (Wk + (idx - 65536)) : (Wov + (idx - 131072)));
    float4 v = *(const float4*)src;
    ushort4 o = { f2bf(v.x), f2bf(v.y), f2bf(v.z), f2bf(v.w) };
    *(ushort4*)(wqkv + idx) = o;
  } else {
    int j = idx - 196608;
    float4 v = *(const float4*)(Wo + j);
    ushort4 o = { f2bf(v.x), f2bf(v.y), f2bf(v.z), f2bf(v.w) };
    *(ushort4*)(wo + j) = o;
  }
}

// ---------------- kernel 1: QKV projection ----------------
__global__ __launch_bounds__(256) void qkv_kernel(
    const float* __restrict__ x, const ushort* __restrict__ wqkv,
    const float* __restrict__ bq, const float* __restrict__ bk,
    const float* __restrict__ bov,
    ushort* __restrict__ Qo, ushort* __restrict__ Ko, ushort* __restrict__ Vt)
{
  __shared__ __attribute__((aligned(16))) ushort xs[32 * 64];
  const int tid  = threadIdx.x;
  const int lane = tid & 63;
  const int wave = tid >> 6;
  const int mt   = wave & 1;
  const int nh   = wave >> 1;
  const int l15  = lane & 15;
  const int l4   = lane >> 4;
  const int row0 = blockIdx.x * 32;

  f32x4 acc[6] = {};

  for (int kc = 0; kc < DM; kc += 64) {
    #pragma unroll
    for (int j = 0; j < 2; ++j) {
      int f4  = tid + j * 256;
      int row = f4 >> 4;
      int c4  = f4 & 15;
      float4 v = *(const float4*)(x + (size_t)(row0 + row) * DM + kc + c4 * 4);
      ushort4 o = { f2bf(v.x), f2bf(v.y), f2bf(v.z), f2bf(v.w) };
      int byteoff = row * 128 + ((c4 * 8) ^ ((row & 7) << 4));
      *(ushort4*)((char*)xs + byteoff) = o;
    }
    __syncthreads();
    #pragma unroll
    for (int c = 0; c < 2; ++c) {
      int arow  = mt * 16 + l15;
      int abyte = arow * 128 + ((((c * 4 + l4)) ^ (arow & 7)) << 4);
      bf16x8 a = *(const bf16x8*)((const char*)xs + abyte);
      #pragma unroll
      for (int i = 0; i < 6; ++i) {
        int nt = nh * 6 + i;
        int brow = nt * 16 + l15;
        bf16x8 b = *(const bf16x8*)(wqkv + (size_t)brow * DM + kc + c * 32 + l4 * 8);
        acc[i] = MFMA16(a, b, acc[i]);
      }
    }
    __syncthreads();
  }

  const float qscale = 1.4426950408889634f / 32.0f;
  #pragma unroll
  for (int i = 0; i < 6; ++i) {
    int nt = nh * 6 + i;
    int n  = nt * 16 + l15;
    #pragma unroll
    for (int r = 0; r < 4; ++r) {
      int grow = row0 + mt * 16 + l4 * 4 + r;
      float v = acc[i][r];
      if (n < 64) {
        Qo[(size_t)grow * 64 + n] = f2bf((v + bq[n]) * qscale);
      } else if (n < 128) {
        int nn = n - 64;
        Ko[(size_t)grow * 64 + nn] = f2bf(v + bk[nn]);
      } else {
        int nn = n - 128;
        int b = grow >> 12, pos = grow & 4095;
        Vt[((size_t)b * 64 + nn) * NCTX + pos] = f2bf(v + bov[nn]);
      }
    }
  }
}

// ---------------- kernel 2: causal flash attention, KV-split ----------------
// Block = one 16-row q strip x 4 waves (each wave = 1/4 of the causal KV range).
// K/V fragments direct from global (L2-hot; one batch per XCD via bb=blk&3).
// Swapped QK^T (S^T = K*Q^T) so P packs to ds_write_b64; no barriers in loop.
__global__ __launch_bounds__(256) void attn_kernel(
    const ushort* __restrict__ Q, const ushort* __restrict__ K,
    const ushort* __restrict__ Vt, ushort* __restrict__ O)
{
  __shared__ __attribute__((aligned(16))) ushort Ps[4][16 * 64]; // per-wave P (swizzled)
  __shared__ __attribute__((aligned(16))) float cO[3][16][64];   // waves 1..3 partial O
  __shared__ float cM[3][16], cL[3][16];

  const int tid  = threadIdx.x;
  const int lane = tid & 63;
  const int wave = tid >> 6;
  const int l15  = lane & 15;
  const int l4   = lane >> 4;

  // block -> (batch, strip): bb=blk&3 pins one batch per XCD; longest strips first
  const int bb    = blockIdx.x & 3;
  const int strip = 255 - (blockIdx.x >> 2);
  const int qs0   = strip * 16;

  const ushort* Qb  = Q  + (size_t)bb * NCTX * 64;
  const ushort* Kb  = K  + (size_t)bb * NCTX * 64;
  const ushort* Vtb = Vt + (size_t)bb * 64 * NCTX;
  ushort* Ob = O + (size_t)bb * NCTX * 64;

  // Q fragment (B-operand of swapped QK^T): lane l15 = q column qs0+l15
  bf16x8 qf[2];
  #pragma unroll
  for (int c = 0; c < 2; ++c)
    qf[c] = *(const bf16x8*)(Qb + (size_t)(qs0 + l15) * 64 + c * 32 + l4 * 8);

  const int ntot = (qs0 + 79) >> 6;        // ceil((qs0+16)/64) kv tiles
  const int cpw  = (ntot + 3) >> 2;
  const int t0 = wave * cpw;
  const int t1 = min(ntot, t0 + cpw);

  float m_run = -1e30f, l_run = 0.f;       // stats for q = qs0+l15 (uniform over l4)
  f32x4 accO[4] = {};                       // O[q=l4*4+r][d=dt*16+l15]
  ushort* Pw = (ushort*)Ps[wave];
  const int swz = (l15 & 7) << 4;

  for (int it = t0; it < t1; ++it) {
    const int kv0 = it * 64;
    // S^T tiles: s4[nt] row = kv local (l4*4+r), col = q (l15)
    f32x4 s4[4] = {};
    __builtin_amdgcn_s_setprio(1);
    #pragma unroll
    for (int c = 0; c < 2; ++c) {
      #pragma unroll
      for (int nt = 0; nt < 4; ++nt) {
        bf16x8 kf = *(const bf16x8*)(Kb + (size_t)(kv0 + nt * 16 + l15) * 64 + c * 32 + l4 * 8);
        s4[nt] = MFMA16(kf, qf[c], s4[nt]);
      }
    }
    __builtin_amdgcn_s_setprio(0);
    // causal mask: kv > q -> -1e30 (only the diagonal-crossing tile)
    if (kv0 + 63 > qs0) {
      #pragma unroll
      for (int nt = 0; nt < 4; ++nt) {
        #pragma unroll
        for (int r = 0; r < 4; ++r) {
          int kvg = kv0 + nt * 16 + l4 * 4 + r;
          if (kvg > qs0 + l15) s4[nt][r] = -1e30f;
        }
      }
    }
    // online softmax for q=l15 (16 regs + 4-lane group over l4: xor 16,32)
    float mx = -1e30f;
    #pragma unroll
    for (int nt = 0; nt < 4; ++nt)
      #pragma unroll
      for (int r = 0; r < 4; ++r) mx = fmaxf(mx, s4[nt][r]);
    mx = fmaxf(mx, __shfl_xor(mx, 16));
    mx = fmaxf(mx, __shfl_xor(mx, 32));
    float mn = fmaxf(m_run, mx);
    float alpha = exp2f(m_run - mn);
    m_run = mn;
    float sm = 0.f;
    #pragma unroll
    for (int nt = 0; nt < 4; ++nt)
      #pragma unroll
      for (int r = 0; r < 4; ++r) {
        float p = exp2f(s4[nt][r] - mn);
        s4[nt][r] = p; sm += p;
      }
    sm += __shfl_xor(sm, 16);
    sm += __shfl_xor(sm, 32);
    l_run = l_run * alpha + sm;
    // rescale accO rows (q=l4*4+r) by that row's alpha
    #pragma unroll
    for (int r = 0; r < 4; ++r) {
      float ar = __shfl(alpha, (lane & 48) | (l4 * 4 + r));
      #pragma unroll
      for (int dt = 0; dt < 4; ++dt) accO[dt][r] *= ar;
    }
    // P[q=l15][kv=nt*16+l4*4 ..+3] -> packed b64 writes, XOR-swizzled
    #pragma unroll
    for (int nt = 0; nt < 4; ++nt) {
      ushort4 pw = { f2bf(s4[nt][0]), f2bf(s4[nt][1]), f2bf(s4[nt][2]), f2bf(s4[nt][3]) };
      int byteoff = l15 * 128 + (((nt * 32 + l4 * 8)) ^ swz);
      *(ushort4*)((char*)Pw + byteoff) = pw;
    }
    // O += P @ V : A = P rows (q), B = V^T rows (d)
    #pragma unroll
    for (int c = 0; c < 2; ++c) {
      bf16x8 pa = *(const bf16x8*)((const char*)Pw + l15 * 128 + ((c * 64 + l4 * 16) ^ swz));
      __builtin_amdgcn_s_setprio(1);
      #pragma unroll
      for (int dt = 0; dt < 4; ++dt) {
        bf16x8 vb = *(const bf16x8*)(Vtb + (size_t)(dt * 16 + l15) * NCTX + kv0 + c * 32 + l4 * 8);
        accO[dt] = MFMA16(pa, vb, accO[dt]);
      }
      __builtin_amdgcn_s_setprio(0);
    }
  }

  // ---- merge the 4 KV-split partials through LDS ----
  if (wave != 0) {
    #pragma unroll
    for (int dt = 0; dt < 4; ++dt)
      #pragma unroll
      for (int r = 0; r < 4; ++r)
        cO[wave - 1][l4 * 4 + r][dt * 16 + l15] = accO[dt][r];
    if (l4 == 0) { cM[wave - 1][l15] = m_run; cL[wave - 1][l15] = l_run; }
  }
  __syncthreads();
  if (wave == 0) {
    float Ms = m_run;
    #pragma unroll
    for (int w = 0; w < 3; ++w) Ms = fmaxf(Ms, cM[w][l15]);
    float f0 = exp2f(m_run - Ms);
    float fw[3];
    float L = l_run * f0;
    #pragma unroll
    for (int w = 0; w < 3; ++w) { fw[w] = exp2f(cM[w][l15] - Ms); L += cL[w][l15] * fw[w]; }
    float invL = 1.0f / L;
    #pragma unroll
    for (int r = 0; r < 4; ++r) {
      int q = l4 * 4 + r;
      int src = (lane & 48) | q;
      float f0r = __shfl(f0, src);
      float iLr = __shfl(invL, src);
      float fwr[3];
      #pragma unroll
      for (int w = 0; w < 3; ++w) fwr[w] = __shfl(fw[w], src);
      #pragma unroll
      for (int dt = 0; dt < 4; ++dt) {
        float o = accO[dt][r] * f0r;
        #pragma unroll
        for (int w = 0; w < 3; ++w) o += fwr[w] * cO[w][q][dt * 16 + l15];
        Ob[(size_t)(qs0 + q) * 64 + dt * 16 + l15] = f2bf(o * iLr);
      }
    }
  }
}

// ---------------- kernel 3: output projection ----------------
__global__ __launch_bounds__(256) void proj_kernel(
    const ushort* __restrict__ O, const ushort* __restrict__ wo,
    const float* __restrict__ bo, float* __restrict__ out)
{
  const int tid  = threadIdx.x;
  const int lane = tid & 63;
  const int wave = tid >> 6;
  const int l15  = lane & 15;
  const int l4   = lane >> 4;
  const int mb = (blockIdx.x >> 2) * 64;
  const int nb = (blockIdx.x & 3) * 256;

  bf16x8 a[2];
  #pragma unroll
  for (int c = 0; c < 2; ++c)
    a[c] = *(const bf16x8*)(O + (size_t)(mb + wave * 16 + l15) * 64 + c * 32 + l4 * 8);

  f32x4 acc[16] = {};
  #pragma unroll
  for (int nt = 0; nt < 16; ++nt) {
    int n = nb + nt * 16 + l15;
    #pragma unroll
    for (int c = 0; c < 2; ++c) {
      bf16x8 b = *(const bf16x8*)(wo + (size_t)n * 64 + c * 32 + l4 * 8);
      acc[nt] = MFMA16(a[c], b, acc[nt]);
    }
  }
  #pragma unroll
  for (int nt = 0; nt < 16; ++nt) {
    int n = nb + nt * 16 + l15;
    float bv = bo[n];
    #pragma unroll
    for (int r = 0; r < 4; ++r) {
      int m = mb + wave * 16 + l4 * 4 + r;
      out[(size_t)m * 1024 + n] = acc[nt][r] + bv;
    }
  }
}

extern "C" void kernel_launch(void* const* d_in, const int* in_sizes, int n_in,
                              void* d_out, int out_size, void* d_ws, size_t ws_size,
                              hipStream_t stream) {
  const float* x   = (const float*)d_in[0];
  const float* Wq  = (const float*)d_in[1];
  const float* bq  = (const float*)d_in[2];
  const float* Wk  = (const float*)d_in[3];
  const float* bk  = (const float*)d_in[4];
  const float* Wov = (const float*)d_in[5];
  const float* bov = (const float*)d_in[6];
  const float* Wo  = (const float*)d_in[7];
  const float* bo  = (const float*)d_in[8];
  float* out = (float*)d_out;

  char* ws = (char*)d_ws;
  ushort* wqkv = (ushort*)(ws);
  ushort* wo   = (ushort*)(ws + 393216);
  ushort* Qw   = (ushort*)(ws + 524288);
  ushort* Kw   = (ushort*)(ws + 524288 + 2097152);
  ushort* Vtw  = (ushort*)(ws + 524288 + 2 * 2097152);
  ushort* Ow   = (ushort*)(ws + 524288 + 3 * 2097152);

  wconv_kernel<<<256, 256, 0, stream>>>(Wq, Wk, Wov, Wo, wqkv, wo);
  qkv_kernel<<<512, 256, 0, stream>>>(x, wqkv, bq, bk, bov, Qw, Kw, Vtw);
  attn_kernel<<<1024, 256, 0, stream>>>(Qw, Kw, Vtw, Ow);
  proj_kernel<<<1024, 256, 0, stream>>>(Ow, wo, bo, out);
}

// Round 4
// 249.098 us; speedup vs baseline: 1.2403x; 1.0854x over previous
//
#include <hip/hip_runtime.h>

#define DM 1024
#define DH 64
#define NBATCH 4
#define NCTX 4096
#define MTOT (NBATCH*NCTX)

typedef __bf16 bf16x8 __attribute__((ext_vector_type(8)));
typedef float f32x4 __attribute__((ext_vector_type(4)));

#define MFMA16(a,b,c) __builtin_amdgcn_mfma_f32_16x16x32_bf16(a,b,c,0,0,0)

__device__ inline ushort f2bf(float f) {
  unsigned u = __builtin_bit_cast(unsigned, f);
  u += 0x7fffu + ((u >> 16) & 1u);
  return (ushort)(u >> 16);
}

// ---------------- kernel 0: weight fp32 -> bf16 ----------------
__global__ __launch_bounds__(256) void wconv_kernel(
    const float* __restrict__ Wq, const float* __restrict__ Wk,
    const float* __restrict__ Wov, const float* __restrict__ Wo,
    ushort* __restrict__ wqkv, ushort* __restrict__ wo)
{
  int idx = (blockIdx.x * 256 + threadIdx.x) * 4;
  if (idx < 196608) {
    const float* src = (idx < 65536) ? (Wq + idx)
                     : (idx < 131072 ? (Wk + (idx - 65536)) : (Wov + (idx - 131072)));
    float4 v = *(const float4*)src;
    ushort4 o = { f2bf(v.x), f2bf(v.y), f2bf(v.z), f2bf(v.w) };
    *(ushort4*)(wqkv + idx) = o;
  } else {
    int j = idx - 196608;
    float4 v = *(const float4*)(Wo + j);
    ushort4 o = { f2bf(v.x), f2bf(v.y), f2bf(v.z), f2bf(v.w) };
    *(ushort4*)(wo + j) = o;
  }
}

// ---------------- kernel 1: QKV projection ----------------
// Stage full 32x1024 x-tile to LDS (bf16, XOR-swizzled) once; then a
// barrier-free K-loop: weights direct from L2.
__global__ __launch_bounds__(256) void qkv_kernel(
    const float* __restrict__ x, const ushort* __restrict__ wqkv,
    const float* __restrict__ bq, const float* __restrict__ bk,
    const float* __restrict__ bov,
    ushort* __restrict__ Qo, ushort* __restrict__ Ko, ushort* __restrict__ Vt)
{
  __shared__ __attribute__((aligned(16))) ushort xs[32 * 1024];  // 64 KB
  const int tid  = threadIdx.x;
  const int lane = tid & 63;
  const int wave = tid >> 6;
  const int mt   = wave & 1;
  const int nh   = wave >> 1;
  const int l15  = lane & 15;
  const int l4   = lane >> 4;
  const int row0 = blockIdx.x * 32;

  // stage: 8192 float4s by 256 threads (32 each), coalesced rows
  #pragma unroll 8
  for (int i = 0; i < 32; ++i) {
    int f4  = tid + i * 256;
    int row = f4 >> 8;           // 256 float4 per row
    int c4  = f4 & 255;
    float4 v = *(const float4*)(x + (size_t)(row0 + row) * DM + c4 * 4);
    ushort4 o = { f2bf(v.x), f2bf(v.y), f2bf(v.z), f2bf(v.w) };
    int byteoff = row * 2048 + ((c4 * 8) ^ ((row & 7) << 4));
    *(ushort4*)((char*)xs + byteoff) = o;
  }
  __syncthreads();

  f32x4 acc[6] = {};
  const int arow = mt * 16 + l15;
  const int aswz = (arow & 7) << 4;
  #pragma unroll 4
  for (int cc = 0; cc < 32; ++cc) {
    bf16x8 a = *(const bf16x8*)((const char*)xs + arow * 2048 + ((cc * 64 + l4 * 16) ^ aswz));
    #pragma unroll
    for (int i = 0; i < 6; ++i) {
      int brow = (nh * 6 + i) * 16 + l15;
      bf16x8 b = *(const bf16x8*)(wqkv + (size_t)brow * DM + cc * 32 + l4 * 8);
      acc[i] = MFMA16(a, b, acc[i]);
    }
  }

  const float qscale = 1.4426950408889634f / 32.0f;  // log2(e)/sqrt(d_model)
  #pragma unroll
  for (int i = 0; i < 6; ++i) {
    int nt = nh * 6 + i;
    int n  = nt * 16 + l15;
    #pragma unroll
    for (int r = 0; r < 4; ++r) {
      int grow = row0 + mt * 16 + l4 * 4 + r;
      float v = acc[i][r];
      if (n < 64) {
        Qo[(size_t)grow * 64 + n] = f2bf((v + bq[n]) * qscale);
      } else if (n < 128) {
        int nn = n - 64;
        Ko[(size_t)grow * 64 + nn] = f2bf(v + bk[nn]);
      } else {
        int nn = n - 128;
        int b = grow >> 12, pos = grow & 4095;
        Vt[((size_t)b * 64 + nn) * NCTX + pos] = f2bf(v + bov[nn]);
      }
    }
  }
}

// ---------------- kernel 2: fused flash attention + output projection ----
// Block = one 16-row q strip; 4 waves KV-split; merge via LDS; then all 4
// waves do the 16x1024 output GEMM (wo L2-hot) and store fp32 out.
__global__ __launch_bounds__(256) void attn_kernel(
    const ushort* __restrict__ Q, const ushort* __restrict__ K,
    const ushort* __restrict__ Vt, const ushort* __restrict__ wo,
    const float* __restrict__ bo, float* __restrict__ out)
{
  __shared__ __attribute__((aligned(16))) ushort Ps[4][16 * 64];
  __shared__ __attribute__((aligned(16))) float cO[3][16][64];
  __shared__ float cM[3][16], cL[3][16];
  __shared__ __attribute__((aligned(16))) ushort O_lds[16 * 64];

  const int tid  = threadIdx.x;
  const int lane = tid & 63;
  const int wave = tid >> 6;
  const int l15  = lane & 15;
  const int l4   = lane >> 4;

  const int bb    = blockIdx.x & 3;
  const int strip = 255 - (blockIdx.x >> 2);
  const int qs0   = strip * 16;

  const ushort* Qb  = Q  + (size_t)bb * NCTX * 64;
  const ushort* Kb  = K  + (size_t)bb * NCTX * 64;
  const ushort* Vtb = Vt + (size_t)bb * 64 * NCTX;

  bf16x8 qf[2];
  #pragma unroll
  for (int c = 0; c < 2; ++c)
    qf[c] = *(const bf16x8*)(Qb + (size_t)(qs0 + l15) * 64 + c * 32 + l4 * 8);

  const int ntot = (qs0 + 79) >> 6;
  const int cpw  = (ntot + 3) >> 2;
  const int t0 = wave * cpw;
  const int t1 = min(ntot, t0 + cpw);

  float m_run = -1e30f, l_run = 0.f;
  f32x4 accO[4] = {};
  ushort* Pw = (ushort*)Ps[wave];
  const int swz = (l15 & 7) << 4;

  for (int it = t0; it < t1; ++it) {
    const int kv0 = it * 64;
    f32x4 s4[4] = {};
    __builtin_amdgcn_s_setprio(1);
    #pragma unroll
    for (int c = 0; c < 2; ++c) {
      #pragma unroll
      for (int nt = 0; nt < 4; ++nt) {
        bf16x8 kf = *(const bf16x8*)(Kb + (size_t)(kv0 + nt * 16 + l15) * 64 + c * 32 + l4 * 8);
        s4[nt] = MFMA16(kf, qf[c], s4[nt]);
      }
    }
    __builtin_amdgcn_s_setprio(0);
    if (kv0 + 63 > qs0) {
      #pragma unroll
      for (int nt = 0; nt < 4; ++nt) {
        #pragma unroll
        for (int r = 0; r < 4; ++r) {
          int kvg = kv0 + nt * 16 + l4 * 4 + r;
          if (kvg > qs0 + l15) s4[nt][r] = -1e30f;
        }
      }
    }
    float mx = -1e30f;
    #pragma unroll
    for (int nt = 0; nt < 4; ++nt)
      #pragma unroll
      for (int r = 0; r < 4; ++r) mx = fmaxf(mx, s4[nt][r]);
    mx = fmaxf(mx, __shfl_xor(mx, 16));
    mx = fmaxf(mx, __shfl_xor(mx, 32));
    float mn = fmaxf(m_run, mx);
    float alpha = exp2f(m_run - mn);
    m_run = mn;
    float sm = 0.f;
    #pragma unroll
    for (int nt = 0; nt < 4; ++nt)
      #pragma unroll
      for (int r = 0; r < 4; ++r) {
        float p = exp2f(s4[nt][r] - mn);
        s4[nt][r] = p; sm += p;
      }
    sm += __shfl_xor(sm, 16);
    sm += __shfl_xor(sm, 32);
    l_run = l_run * alpha + sm;
    #pragma unroll
    for (int r = 0; r < 4; ++r) {
      float ar = __shfl(alpha, (lane & 48) | (l4 * 4 + r));
      #pragma unroll
      for (int dt = 0; dt < 4; ++dt) accO[dt][r] *= ar;
    }
    #pragma unroll
    for (int nt = 0; nt < 4; ++nt) {
      ushort4 pw = { f2bf(s4[nt][0]), f2bf(s4[nt][1]), f2bf(s4[nt][2]), f2bf(s4[nt][3]) };
      int byteoff = l15 * 128 + (((nt * 32 + l4 * 8)) ^ swz);
      *(ushort4*)((char*)Pw + byteoff) = pw;
    }
    #pragma unroll
    for (int c = 0; c < 2; ++c) {
      bf16x8 pa = *(const bf16x8*)((const char*)Pw + l15 * 128 + ((c * 64 + l4 * 16) ^ swz));
      __builtin_amdgcn_s_setprio(1);
      #pragma unroll
      for (int dt = 0; dt < 4; ++dt) {
        bf16x8 vb = *(const bf16x8*)(Vtb + (size_t)(dt * 16 + l15) * NCTX + kv0 + c * 32 + l4 * 8);
        accO[dt] = MFMA16(pa, vb, accO[dt]);
      }
      __builtin_amdgcn_s_setprio(0);
    }
  }

  // ---- merge KV-split partials; wave0 writes final O (bf16) to LDS ----
  if (wave != 0) {
    #pragma unroll
    for (int dt = 0; dt < 4; ++dt)
      #pragma unroll
      for (int r = 0; r < 4; ++r)
        cO[wave - 1][l4 * 4 + r][dt * 16 + l15] = accO[dt][r];
    if (l4 == 0) { cM[wave - 1][l15] = m_run; cL[wave - 1][l15] = l_run; }
  }
  __syncthreads();
  if (wave == 0) {
    float Ms = m_run;
    #pragma unroll
    for (int w = 0; w < 3; ++w) Ms = fmaxf(Ms, cM[w][l15]);
    float f0 = exp2f(m_run - Ms);
    float fw[3];
    float L = l_run * f0;
    #pragma unroll
    for (int w = 0; w < 3; ++w) { fw[w] = exp2f(cM[w][l15] - Ms); L += cL[w][l15] * fw[w]; }
    float invL = 1.0f / L;
    #pragma unroll
    for (int r = 0; r < 4; ++r) {
      int q = l4 * 4 + r;
      int src = (lane & 48) | q;
      float f0r = __shfl(f0, src);
      float iLr = __shfl(invL, src);
      float fwr[3];
      #pragma unroll
      for (int w = 0; w < 3; ++w) fwr[w] = __shfl(fw[w], src);
      int qswz = (q & 7) << 4;
      #pragma unroll
      for (int dt = 0; dt < 4; ++dt) {
        float o = accO[dt][r] * f0r;
        #pragma unroll
        for (int w = 0; w < 3; ++w) o += fwr[w] * cO[w][q][dt * 16 + l15];
        int byteoff = q * 128 + ((dt * 32 + l15 * 2) ^ qswz);
        *(ushort*)((char*)O_lds + byteoff) = f2bf(o * iLr);
      }
    }
  }
  __syncthreads();

  // ---- fused output projection: 16 q rows x 1024 cols, wave n-split ----
  bf16x8 oa[2];
  const int oswz = (l15 & 7) << 4;
  #pragma unroll
  for (int c = 0; c < 2; ++c)
    oa[c] = *(const bf16x8*)((const char*)O_lds + l15 * 128 + ((c * 64 + l4 * 16) ^ oswz));

  f32x4 pacc[16] = {};
  #pragma unroll
  for (int nt = 0; nt < 16; ++nt) {
    int n = wave * 256 + nt * 16 + l15;
    #pragma unroll
    for (int c = 0; c < 2; ++c) {
      bf16x8 b = *(const bf16x8*)(wo + (size_t)n * 64 + c * 32 + l4 * 8);
      pacc[nt] = MFMA16(oa[c], b, pacc[nt]);
    }
  }
  const size_t orow0 = (size_t)bb * NCTX + qs0;
  #pragma unroll
  for (int nt = 0; nt < 16; ++nt) {
    int n = wave * 256 + nt * 16 + l15;
    float bv = bo[n];
    #pragma unroll
    for (int r = 0; r < 4; ++r) {
      out[(orow0 + l4 * 4 + r) * 1024 + n] = pacc[nt][r] + bv;
    }
  }
}

extern "C" void kernel_launch(void* const* d_in, const int* in_sizes, int n_in,
                              void* d_out, int out_size, void* d_ws, size_t ws_size,
                              hipStream_t stream) {
  const float* x   = (const float*)d_in[0];
  const float* Wq  = (const float*)d_in[1];
  const float* bq  = (const float*)d_in[2];
  const float* Wk  = (const float*)d_in[3];
  const float* bk  = (const float*)d_in[4];
  const float* Wov = (const float*)d_in[5];
  const float* bov = (const float*)d_in[6];
  const float* Wo  = (const float*)d_in[7];
  const float* bo  = (const float*)d_in[8];
  float* out = (float*)d_out;

  char* ws = (char*)d_ws;
  ushort* wqkv = (ushort*)(ws);
  ushort* wo   = (ushort*)(ws + 393216);
  ushort* Qw   = (ushort*)(ws + 524288);
  ushort* Kw   = (ushort*)(ws + 524288 + 2097152);
  ushort* Vtw  = (ushort*)(ws + 524288 + 2 * 2097152);

  wconv_kernel<<<256, 256, 0, stream>>>(Wq, Wk, Wov, Wo, wqkv, wo);
  qkv_kernel<<<512, 256, 0, stream>>>(x, wqkv, bq, bk, bov, Qw, Kw, Vtw);
  attn_kernel<<<1024, 256, 0, stream>>>(Qw, Kw, Vtw, wo, bo, out);
}

// Round 5
// 200.381 us; speedup vs baseline: 1.5418x; 1.2431x over previous
//
#include <hip/hip_runtime.h>

#define DM 1024
#define DH 64
#define NBATCH 4
#define NCTX 4096
#define MTOT (NBATCH*NCTX)

typedef __bf16 bf16x8 __attribute__((ext_vector_type(8)));
typedef float f32x4 __attribute__((ext_vector_type(4)));

#define MFMA16(a,b,c) __builtin_amdgcn_mfma_f32_16x16x32_bf16(a,b,c,0,0,0)

__device__ inline ushort f2bf(float f) {
  unsigned u = __builtin_bit_cast(unsigned, f);
  u += 0x7fffu + ((u >> 16) & 1u);
  return (ushort)(u >> 16);
}

// Packed fragment-linear layout for all global MFMA operands:
//   addr(ushort) = ((tile*NC + chunk)*64 + lane)*8 + j
// holding M[tile*16 + (lane&15)][chunk*32 + (lane>>4)*8 + j].
// A wave's fragment load is then 64 lanes x 16B = 1KB contiguous.

// ---------------- kernel 0: weight fp32 -> bf16, packed ----------------
__global__ __launch_bounds__(256) void wconv_kernel(
    const float* __restrict__ Wq, const float* __restrict__ Wk,
    const float* __restrict__ Wov, const float* __restrict__ Wo,
    ushort* __restrict__ wqkvp, ushort* __restrict__ wop)
{
  int idx = (blockIdx.x * 256 + threadIdx.x) * 4;
  if (idx < 196608) {
    const float* src = (idx < 65536) ? (Wq + idx)
                     : (idx < 131072 ? (Wk + (idx - 65536)) : (Wov + (idx - 131072)));
    float4 v = *(const float4*)src;
    ushort4 o = { f2bf(v.x), f2bf(v.y), f2bf(v.z), f2bf(v.w) };
    int row = idx >> 10, col = idx & 1023;    // Wcat [192][1024]
    int T = row >> 4, l15 = row & 15, C = col >> 5, l4 = (col >> 3) & 3, j = col & 7;
    *(ushort4*)(wqkvp + (((T * 32 + C) * 64 + l4 * 16 + l15) * 8 + j)) = o;
  } else {
    int k = idx - 196608;                      // Wo [1024][64]
    float4 v = *(const float4*)(Wo + k);
    ushort4 o = { f2bf(v.x), f2bf(v.y), f2bf(v.z), f2bf(v.w) };
    int row = k >> 6, col = k & 63;
    int T = row >> 4, l15 = row & 15, C = col >> 5, l4 = (col >> 3) & 3, j = col & 7;
    *(ushort4*)(wop + (((T * 2 + C) * 64 + l4 * 16 + l15) * 8 + j)) = o;
  }
}

// ---------------- kernel 1: QKV projection ----------------
// Stage full 32x1024 x-tile to LDS once; barrier-free K-loop with packed
// weight fragments (contiguous 1KB wave loads); epilogue scatter-writes
// Q/K/V in packed fragment layout.
__global__ __launch_bounds__(256) void qkv_kernel(
    const float* __restrict__ x, const ushort* __restrict__ wqkvp,
    const float* __restrict__ bq, const float* __restrict__ bk,
    const float* __restrict__ bov,
    ushort* __restrict__ Qp, ushort* __restrict__ Kp, ushort* __restrict__ Vp)
{
  __shared__ __attribute__((aligned(16))) ushort xs[32 * 1024];  // 64 KB
  const int tid  = threadIdx.x;
  const int lane = tid & 63;
  const int wave = tid >> 6;
  const int mt   = wave & 1;
  const int nh   = wave >> 1;
  const int l15  = lane & 15;
  const int l4   = lane >> 4;
  const int row0 = blockIdx.x * 32;

  #pragma unroll 8
  for (int i = 0; i < 32; ++i) {
    int f4  = tid + i * 256;
    int row = f4 >> 8;
    int c4  = f4 & 255;
    float4 v = *(const float4*)(x + (size_t)(row0 + row) * DM + c4 * 4);
    ushort4 o = { f2bf(v.x), f2bf(v.y), f2bf(v.z), f2bf(v.w) };
    int byteoff = row * 2048 + ((c4 * 8) ^ ((row & 7) << 4));
    *(ushort4*)((char*)xs + byteoff) = o;
  }
  __syncthreads();

  f32x4 acc[6] = {};
  const int arow = mt * 16 + l15;
  const int aswz = (arow & 7) << 4;
  #pragma unroll 4
  for (int cc = 0; cc < 32; ++cc) {
    bf16x8 a = *(const bf16x8*)((const char*)xs + arow * 2048 + ((cc * 64 + l4 * 16) ^ aswz));
    #pragma unroll
    for (int i = 0; i < 6; ++i) {
      bf16x8 b = *(const bf16x8*)(wqkvp + (((size_t)(nh * 6 + i) * 32 + cc) * 64 + lane) * 8);
      acc[i] = MFMA16(a, b, acc[i]);
    }
  }

  const float qscale = 1.4426950408889634f / 32.0f;  // log2(e)/sqrt(d_model)
  #pragma unroll
  for (int i = 0; i < 6; ++i) {
    int n = (nh * 6 + i) * 16 + l15;
    #pragma unroll
    for (int r = 0; r < 4; ++r) {
      int grow = row0 + mt * 16 + l4 * 4 + r;
      float v = acc[i][r];
      if (n < 64) {
        size_t a = (((size_t)(grow >> 4) * 2 + (n >> 5)) * 64 + ((n >> 3) & 3) * 16 + (grow & 15)) * 8 + (n & 7);
        Qp[a] = f2bf((v + bq[n]) * qscale);
      } else if (n < 128) {
        int nn = n - 64;
        size_t a = (((size_t)(grow >> 4) * 2 + (nn >> 5)) * 64 + ((nn >> 3) & 3) * 16 + (grow & 15)) * 8 + (nn & 7);
        Kp[a] = f2bf(v + bk[nn]);
      } else {
        int d = n - 128;
        int b = grow >> 12, pos = grow & 4095;
        size_t a = (size_t)b * 262144 +
                   (((size_t)(d >> 4) * 128 + (pos >> 5)) * 64 + ((pos >> 3) & 3) * 16 + (d & 15)) * 8 + (pos & 7);
        Vp[a] = f2bf(v + bov[d]);
      }
    }
  }
}

// ---------------- kernel 2: fused flash attention + output projection ----
// Block = one 16-row q strip; 4 waves KV-split with 2-tile interleaved
// inner loop; packed K/V/Q fragment loads (contiguous); merge via LDS;
// fused 16x1024 output GEMM epilogue.
__global__ __launch_bounds__(256) void attn_kernel(
    const ushort* __restrict__ Qp, const ushort* __restrict__ Kp,
    const ushort* __restrict__ Vp, const ushort* __restrict__ wop,
    const float* __restrict__ bo, float* __restrict__ out)
{
  __shared__ __attribute__((aligned(16))) ushort Ps[4][16 * 128]; // 16 KB
  __shared__ __attribute__((aligned(16))) float cO[3][16][64];    // 12 KB
  __shared__ float cM[3][16], cL[3][16];
  __shared__ __attribute__((aligned(16))) ushort O_lds[16 * 64];

  const int tid  = threadIdx.x;
  const int lane = tid & 63;
  const int wave = tid >> 6;
  const int l15  = lane & 15;
  const int l4   = lane >> 4;

  const int bb    = blockIdx.x & 3;
  const int strip = 255 - (blockIdx.x >> 2);
  const int qs0   = strip * 16;

  const size_t vbase = (size_t)bb * 262144;
  const int Tq = bb * 256 + strip;

  bf16x8 qf[2];
  #pragma unroll
  for (int c = 0; c < 2; ++c)
    qf[c] = *(const bf16x8*)(Qp + (((size_t)Tq * 2 + c) * 64 + lane) * 8);

  const int ntot = (qs0 + 79) >> 6;
  const int cpw  = (ntot + 3) >> 2;
  const int t0 = wave * cpw;
  const int t1 = min(ntot, t0 + cpw);

  float m_run = -1e30f, l_run = 0.f;
  f32x4 accO[4] = {};
  ushort* Pw = (ushort*)Ps[wave];
  const int swz = (l15 & 7) << 4;

  int it = t0;
  // ---- paired KV tiles ----
  for (; it + 1 < t1; it += 2) {
    const int kv0 = it * 64, kv1 = kv0 + 64;
    const int Tk0 = bb * 256 + (kv0 >> 4);
    f32x4 s4[8] = {};
    __builtin_amdgcn_s_setprio(1);
    #pragma unroll
    for (int c = 0; c < 2; ++c) {
      #pragma unroll
      for (int nt = 0; nt < 8; ++nt) {
        bf16x8 kf = *(const bf16x8*)(Kp + (((size_t)(Tk0 + nt) * 2 + c) * 64 + lane) * 8);
        s4[nt] = MFMA16(kf, qf[c], s4[nt]);
      }
    }
    __builtin_amdgcn_s_setprio(0);
    // only tile B can cross the diagonal inside a pair
    if (kv1 + 63 > qs0) {
      #pragma unroll
      for (int nt = 0; nt < 4; ++nt) {
        #pragma unroll
        for (int r = 0; r < 4; ++r) {
          int kvg = kv1 + nt * 16 + l4 * 4 + r;
          if (kvg > qs0 + l15) s4[4 + nt][r] = -1e30f;
        }
      }
    }
    // joint online softmax over 32 values (q = l15)
    float mx = -1e30f;
    #pragma unroll
    for (int nt = 0; nt < 8; ++nt)
      #pragma unroll
      for (int r = 0; r < 4; ++r) mx = fmaxf(mx, s4[nt][r]);
    mx = fmaxf(mx, __shfl_xor(mx, 16));
    mx = fmaxf(mx, __shfl_xor(mx, 32));
    float mn = fmaxf(m_run, mx);
    float alpha = exp2f(m_run - mn);
    m_run = mn;
    float sm = 0.f;
    #pragma unroll
    for (int nt = 0; nt < 8; ++nt)
      #pragma unroll
      for (int r = 0; r < 4; ++r) {
        float p = exp2f(s4[nt][r] - mn);
        s4[nt][r] = p; sm += p;
      }
    sm += __shfl_xor(sm, 16);
    sm += __shfl_xor(sm, 32);
    l_run = l_run * alpha + sm;
    #pragma unroll
    for (int r = 0; r < 4; ++r) {
      float ar = __shfl(alpha, (lane & 48) | (l4 * 4 + r));
      #pragma unroll
      for (int dt = 0; dt < 4; ++dt) accO[dt][r] *= ar;
    }
    // P -> LDS: tile A at byte 0..127, tile B at 128..255 (row stride 256B)
    #pragma unroll
    for (int nt = 0; nt < 4; ++nt) {
      ushort4 pwA = { f2bf(s4[nt][0]), f2bf(s4[nt][1]), f2bf(s4[nt][2]), f2bf(s4[nt][3]) };
      ushort4 pwB = { f2bf(s4[4+nt][0]), f2bf(s4[4+nt][1]), f2bf(s4[4+nt][2]), f2bf(s4[4+nt][3]) };
      *(ushort4*)((char*)Pw + l15 * 256 + ((nt * 32 + l4 * 8) ^ swz)) = pwA;
      *(ushort4*)((char*)Pw + l15 * 256 + ((128 + nt * 32 + l4 * 8) ^ swz)) = pwB;
    }
    // O += P @ V over 128 kv (4 chunks)
    #pragma unroll
    for (int c = 0; c < 4; ++c) {
      bf16x8 pa = *(const bf16x8*)((const char*)Pw + l15 * 256 + ((c * 64 + l4 * 16) ^ swz));
      __builtin_amdgcn_s_setprio(1);
      #pragma unroll
      for (int dt = 0; dt < 4; ++dt) {
        bf16x8 vb = *(const bf16x8*)(Vp + vbase + (((size_t)dt * 128 + (kv0 >> 5) + c) * 64 + lane) * 8);
        accO[dt] = MFMA16(pa, vb, accO[dt]);
      }
      __builtin_amdgcn_s_setprio(0);
    }
  }
  // ---- remainder single tile ----
  if (it < t1) {
    const int kv0 = it * 64;
    const int Tk0 = bb * 256 + (kv0 >> 4);
    f32x4 s4[4] = {};
    __builtin_amdgcn_s_setprio(1);
    #pragma unroll
    for (int c = 0; c < 2; ++c) {
      #pragma unroll
      for (int nt = 0; nt < 4; ++nt) {
        bf16x8 kf = *(const bf16x8*)(Kp + (((size_t)(Tk0 + nt) * 2 + c) * 64 + lane) * 8);
        s4[nt] = MFMA16(kf, qf[c], s4[nt]);
      }
    }
    __builtin_amdgcn_s_setprio(0);
    if (kv0 + 63 > qs0) {
      #pragma unroll
      for (int nt = 0; nt < 4; ++nt) {
        #pragma unroll
        for (int r = 0; r < 4; ++r) {
          int kvg = kv0 + nt * 16 + l4 * 4 + r;
          if (kvg > qs0 + l15) s4[nt][r] = -1e30f;
        }
      }
    }
    float mx = -1e30f;
    #pragma unroll
    for (int nt = 0; nt < 4; ++nt)
      #pragma unroll
      for (int r = 0; r < 4; ++r) mx = fmaxf(mx, s4[nt][r]);
    mx = fmaxf(mx, __shfl_xor(mx, 16));
    mx = fmaxf(mx, __shfl_xor(mx, 32));
    float mn = fmaxf(m_run, mx);
    float alpha = exp2f(m_run - mn);
    m_run = mn;
    float sm = 0.f;
    #pragma unroll
    for (int nt = 0; nt < 4; ++nt)
      #pragma unroll
      for (int r = 0; r < 4; ++r) {
        float p = exp2f(s4[nt][r] - mn);
        s4[nt][r] = p; sm += p;
      }
    sm += __shfl_xor(sm, 16);
    sm += __shfl_xor(sm, 32);
    l_run = l_run * alpha + sm;
    #pragma unroll
    for (int r = 0; r < 4; ++r) {
      float ar = __shfl(alpha, (lane & 48) | (l4 * 4 + r));
      #pragma unroll
      for (int dt = 0; dt < 4; ++dt) accO[dt][r] *= ar;
    }
    #pragma unroll
    for (int nt = 0; nt < 4; ++nt) {
      ushort4 pw = { f2bf(s4[nt][0]), f2bf(s4[nt][1]), f2bf(s4[nt][2]), f2bf(s4[nt][3]) };
      *(ushort4*)((char*)Pw + l15 * 256 + ((nt * 32 + l4 * 8) ^ swz)) = pw;
    }
    #pragma unroll
    for (int c = 0; c < 2; ++c) {
      bf16x8 pa = *(const bf16x8*)((const char*)Pw + l15 * 256 + ((c * 64 + l4 * 16) ^ swz));
      __builtin_amdgcn_s_setprio(1);
      #pragma unroll
      for (int dt = 0; dt < 4; ++dt) {
        bf16x8 vb = *(const bf16x8*)(Vp + vbase + (((size_t)dt * 128 + (kv0 >> 5) + c) * 64 + lane) * 8);
        accO[dt] = MFMA16(pa, vb, accO[dt]);
      }
      __builtin_amdgcn_s_setprio(0);
    }
  }

  // ---- merge KV-split partials; wave0 writes final O (bf16) to LDS ----
  if (wave != 0) {
    #pragma unroll
    for (int dt = 0; dt < 4; ++dt)
      #pragma unroll
      for (int r = 0; r < 4; ++r)
        cO[wave - 1][l4 * 4 + r][dt * 16 + l15] = accO[dt][r];
    if (l4 == 0) { cM[wave - 1][l15] = m_run; cL[wave - 1][l15] = l_run; }
  }
  __syncthreads();
  if (wave == 0) {
    float Ms = m_run;
    #pragma unroll
    for (int w = 0; w < 3; ++w) Ms = fmaxf(Ms, cM[w][l15]);
    float f0 = exp2f(m_run - Ms);
    float fw[3];
    float L = l_run * f0;
    #pragma unroll
    for (int w = 0; w < 3; ++w) { fw[w] = exp2f(cM[w][l15] - Ms); L += cL[w][l15] * fw[w]; }
    float invL = 1.0f / L;
    #pragma unroll
    for (int r = 0; r < 4; ++r) {
      int q = l4 * 4 + r;
      int src = (lane & 48) | q;
      float f0r = __shfl(f0, src);
      float iLr = __shfl(invL, src);
      float fwr[3];
      #pragma unroll
      for (int w = 0; w < 3; ++w) fwr[w] = __shfl(fw[w], src);
      int qswz = (q & 7) << 4;
      #pragma unroll
      for (int dt = 0; dt < 4; ++dt) {
        float o = accO[dt][r] * f0r;
        #pragma unroll
        for (int w = 0; w < 3; ++w) o += fwr[w] * cO[w][q][dt * 16 + l15];
        int byteoff = q * 128 + ((dt * 32 + l15 * 2) ^ qswz);
        *(ushort*)((char*)O_lds + byteoff) = f2bf(o * iLr);
      }
    }
  }
  __syncthreads();

  // ---- fused output projection: 16 q rows x 1024 cols, wave n-split ----
  bf16x8 oa[2];
  const int oswz = (l15 & 7) << 4;
  #pragma unroll
  for (int c = 0; c < 2; ++c)
    oa[c] = *(const bf16x8*)((const char*)O_lds + l15 * 128 + ((c * 64 + l4 * 16) ^ oswz));

  f32x4 pacc[16] = {};
  #pragma unroll
  for (int nt = 0; nt < 16; ++nt) {
    #pragma unroll
    for (int c = 0; c < 2; ++c) {
      bf16x8 b = *(const bf16x8*)(wop + (((size_t)(wave * 16 + nt) * 2 + c) * 64 + lane) * 8);
      pacc[nt] = MFMA16(oa[c], b, pacc[nt]);
    }
  }
  const size_t orow0 = (size_t)bb * NCTX + qs0;
  #pragma unroll
  for (int nt = 0; nt < 16; ++nt) {
    int n = wave * 256 + nt * 16 + l15;
    float bv = bo[n];
    #pragma unroll
    for (int r = 0; r < 4; ++r) {
      out[(orow0 + l4 * 4 + r) * 1024 + n] = pacc[nt][r] + bv;
    }
  }
}

extern "C" void kernel_launch(void* const* d_in, const int* in_sizes, int n_in,
                              void* d_out, int out_size, void* d_ws, size_t ws_size,
                              hipStream_t stream) {
  const float* x   = (const float*)d_in[0];
  const float* Wq  = (const float*)d_in[1];
  const float* bq  = (const float*)d_in[2];
  const float* Wk  = (const float*)d_in[3];
  const float* bk  = (const float*)d_in[4];
  const float* Wov = (const float*)d_in[5];
  const float* bov = (const float*)d_in[6];
  const float* Wo  = (const float*)d_in[7];
  const float* bo  = (const float*)d_in[8];
  float* out = (float*)d_out;

  char* ws = (char*)d_ws;
  ushort* wqkvp = (ushort*)(ws);                         // 384 KB packed
  ushort* wop   = (ushort*)(ws + 393216);                // 128 KB packed
  ushort* Qpw   = (ushort*)(ws + 524288);                // 2 MiB packed
  ushort* Kpw   = (ushort*)(ws + 524288 + 2097152);
  ushort* Vpw   = (ushort*)(ws + 524288 + 2 * 2097152);

  wconv_kernel<<<256, 256, 0, stream>>>(Wq, Wk, Wov, Wo, wqkvp, wop);
  qkv_kernel<<<512, 256, 0, stream>>>(x, wqkvp, bq, bk, bov, Qpw, Kpw, Vpw);
  attn_kernel<<<1024, 256, 0, stream>>>(Qpw, Kpw, Vpw, wop, bo, out);
}